// Round 5
// baseline (581.163 us; speedup 1.0000x reference)
//
#include <hip/hip_runtime.h>
#include <hip/hip_bf16.h>

typedef __bf16 bf16x8 __attribute__((ext_vector_type(8)));
typedef __bf16 bf16x4 __attribute__((ext_vector_type(4)));
typedef float  f32x4  __attribute__((ext_vector_type(4)));

#define NROW 4096
#define XSTR 384
#define DHEAD 128
#define QBLK 32
#define KVB 128
#define NIT (NROW / KVB)

// 512 threads, target 2 blocks/CU (4 waves/SIMD): VGPR capped at 128.
__launch_bounds__(512, 4)
__global__ void attn_fwd_kernel(const float* __restrict__ x, float* __restrict__ out) {
    // XCD-aware swizzle: 512 blocks / 8 XCDs -> 64 consecutive logical blocks per XCD
    const int bid  = blockIdx.x;
    const int orig = (bid & 7) * 64 + (bid >> 3);
    const int b    = orig >> 7;          // batch 0..3
    const int t0   = (orig & 127) * QBLK;

    const int tid = threadIdx.x;
    const int w   = tid >> 6;            // wave 0..7
    const int wq  = w & 1;               // q-row group (16 rows)
    const int kvq = w >> 1;              // KV quarter: s in [kvq*32, kvq*32+32)
    const int l   = tid & 63;
    const int lr  = l & 15;
    const int lg  = l >> 4;
    const int sq  = kvq * 32;

    // Kt/Vt stride 136 bf16 = 272B: 16B-aligned rows (real ds_read_b128) and
    // bank-step 4 -> 16 rows cover banks 0..31 exactly 2-way (free, m136).
    __shared__ union {
        struct { __bf16 Kt[KVB][136]; __bf16 Vt[DHEAD][136]; } t;   // Kt[s][c], Vt[c][s]
        struct { float O[3][2][16][132]; float m[3][2][16]; float lsum[3][2][16]; } mrg;
    } U;
    // P tile per wave: stride 40 bf16 = 80B: 16B-aligned, bank-step 20 -> 2-way.
    __shared__ __bf16 Pl[8][16][40];

    const float* xb = x + (size_t)b * NROW * XSTR;

    // ---- Q fragments (k-slice of x, cols 128..255), rows t0 + wq*16 + lr ----
    bf16x8 qf[4];
    {
        const float* qrow = xb + (size_t)(t0 + wq * 16 + lr) * XSTR + DHEAD;
        #pragma unroll
        for (int kc = 0; kc < 4; ++kc) {
            const float4 f0 = *(const float4*)(qrow + kc * 32 + lg * 8);
            const float4 f1 = *(const float4*)(qrow + kc * 32 + lg * 8 + 4);
            bf16x8 v;
            v[0] = (__bf16)f0.x; v[1] = (__bf16)f0.y; v[2] = (__bf16)f0.z; v[3] = (__bf16)f0.w;
            v[4] = (__bf16)f1.x; v[5] = (__bf16)f1.y; v[6] = (__bf16)f1.z; v[7] = (__bf16)f1.w;
            qf[kc] = v;
        }
    }

    f32x4 oacc[8];
    #pragma unroll
    for (int i = 0; i < 8; ++i) { f32x4 z = {0.f, 0.f, 0.f, 0.f}; oacc[i] = z; }
    float mrow[4], lrow[4];
    #pragma unroll
    for (int r = 0; r < 4; ++r) { mrow[r] = -1e30f; lrow[r] = 0.f; }

    const float C = 0.08838834764831845f * 1.44269504088896340f; // 1/sqrt(128)*log2(e)

    const int krow = tid >> 5;           // 0..15
    const int kcol = (tid & 31) << 2;    // 0..124

    float4 pk[8], pv[8];

    auto prefetch = [&](int S0) {
        #pragma unroll
        for (int i = 0; i < 8; ++i)
            pk[i] = *(const float4*)(xb + (size_t)(S0 + krow + i * 16) * XSTR + kcol);
        #pragma unroll
        for (int i2 = 0; i2 < 2; ++i2) {
            const int cb = (krow + i2 * 16) << 2;
            #pragma unroll
            for (int r = 0; r < 4; ++r)
                pv[i2 * 4 + r] = *(const float4*)(xb + (size_t)(S0 + kcol + r) * XSTR + 256 + cb);
        }
    };
    auto write_lds = [&]() {
        #pragma unroll
        for (int i = 0; i < 8; ++i) {
            const float* f = (const float*)&pk[i];
            bf16x4 v;
            v[0] = (__bf16)f[0]; v[1] = (__bf16)f[1]; v[2] = (__bf16)f[2]; v[3] = (__bf16)f[3];
            *(bf16x4*)&U.t.Kt[krow + i * 16][kcol] = v;
        }
        #pragma unroll
        for (int i2 = 0; i2 < 2; ++i2) {
            const int cb = (krow + i2 * 16) << 2;
            #pragma unroll
            for (int cc = 0; cc < 4; ++cc) {
                bf16x4 v;
                #pragma unroll
                for (int r = 0; r < 4; ++r)
                    v[r] = (__bf16)((const float*)&pv[i2 * 4 + r])[cc];
                *(bf16x4*)&U.t.Vt[cb + cc][kcol] = v;   // Vt[c][s]
            }
        }
    };

    prefetch(0);
    write_lds();
    __syncthreads();

    for (int it = 0; it < NIT; ++it) {
        if (it + 1 < NIT) prefetch((it + 1) * KVB);   // hide HBM latency under compute

        // ---- QK^T over this wave's 32-s quarter: D[t][s_local] ----
        f32x4 sacc[2];
        #pragma unroll
        for (int st = 0; st < 2; ++st) { f32x4 z = {0.f, 0.f, 0.f, 0.f}; sacc[st] = z; }
        __builtin_amdgcn_s_setprio(1);
        #pragma unroll
        for (int kc = 0; kc < 4; ++kc) {
            #pragma unroll
            for (int st = 0; st < 2; ++st) {
                bf16x8 bf = *(const bf16x8*)&U.t.Kt[sq + st * 16 + lr][kc * 32 + lg * 8];
                sacc[st] = __builtin_amdgcn_mfma_f32_16x16x32_bf16(qf[kc], bf, sacc[st], 0, 0, 0);
            }
        }
        __builtin_amdgcn_s_setprio(0);

        // ---- online softmax over the 32 s of this quarter ----
        float rmax[4], psum[4], alpha[4];
        #pragma unroll
        for (int r = 0; r < 4; ++r) rmax[r] = fmaxf(sacc[0][r], sacc[1][r]);
        #pragma unroll
        for (int mk = 1; mk <= 8; mk <<= 1) {
            #pragma unroll
            for (int r = 0; r < 4; ++r) rmax[r] = fmaxf(rmax[r], __shfl_xor(rmax[r], mk));
        }
        #pragma unroll
        for (int r = 0; r < 4; ++r) {
            float mnew = fmaxf(mrow[r], rmax[r]);
            alpha[r]   = __builtin_amdgcn_exp2f((mrow[r] - mnew) * C);
            mrow[r]    = mnew;
            psum[r]    = 0.f;
        }
        #pragma unroll
        for (int st = 0; st < 2; ++st) {
            #pragma unroll
            for (int r = 0; r < 4; ++r) {
                float p = __builtin_amdgcn_exp2f((sacc[st][r] - mrow[r]) * C);
                psum[r] += p;
                Pl[w][lg * 4 + r][st * 16 + lr] = (__bf16)p;
            }
        }
        #pragma unroll
        for (int mk = 1; mk <= 8; mk <<= 1) {
            #pragma unroll
            for (int r = 0; r < 4; ++r) psum[r] += __shfl_xor(psum[r], mk);
        }
        #pragma unroll
        for (int r = 0; r < 4; ++r) lrow[r] = lrow[r] * alpha[r] + psum[r];
        #pragma unroll
        for (int ct = 0; ct < 8; ++ct) {
            #pragma unroll
            for (int r = 0; r < 4; ++r) oacc[ct][r] *= alpha[r];
        }

        // ---- PV: k = 32 (this wave's quarter) ----
        bf16x8 pa = *(const bf16x8*)&Pl[w][lr][lg * 8];
        __builtin_amdgcn_s_setprio(1);
        #pragma unroll
        for (int ct = 0; ct < 8; ++ct) {
            bf16x8 bv = *(const bf16x8*)&U.t.Vt[ct * 16 + lr][sq + lg * 8];
            oacc[ct] = __builtin_amdgcn_mfma_f32_16x16x32_bf16(pa, bv, oacc[ct], 0, 0, 0);
        }
        __builtin_amdgcn_s_setprio(0);

        __syncthreads();                       // all waves done reading Kt/Vt
        if (it + 1 < NIT) { write_lds(); __syncthreads(); }
    }

    // ---- 4-way exact LSE merge across kv quarters ----
    if (kvq > 0) {
        #pragma unroll
        for (int ct = 0; ct < 8; ++ct) {
            #pragma unroll
            for (int r = 0; r < 4; ++r)
                U.mrg.O[kvq - 1][wq][lg * 4 + r][ct * 16 + lr] = oacc[ct][r];
        }
        if (lr == 0) {
            #pragma unroll
            for (int r = 0; r < 4; ++r) {
                U.mrg.m[kvq - 1][wq][lg * 4 + r]    = mrow[r];
                U.mrg.lsum[kvq - 1][wq][lg * 4 + r] = lrow[r];
            }
        }
    }
    __syncthreads();
    if (kvq == 0) {
        float* orow = out + ((size_t)b * NROW + t0 + wq * 16) * DHEAD;
        #pragma unroll
        for (int r = 0; r < 4; ++r) {
            float mp[3], lp[3];
            #pragma unroll
            for (int p = 0; p < 3; ++p) {
                mp[p] = U.mrg.m[p][wq][lg * 4 + r];
                lp[p] = U.mrg.lsum[p][wq][lg * 4 + r];
            }
            float mm = fmaxf(fmaxf(mrow[r], mp[0]), fmaxf(mp[1], mp[2]));
            const float a0 = __builtin_amdgcn_exp2f((mrow[r] - mm) * C);
            float ap[3];
            float denom = lrow[r] * a0;
            #pragma unroll
            for (int p = 0; p < 3; ++p) {
                ap[p] = __builtin_amdgcn_exp2f((mp[p] - mm) * C);
                denom += lp[p] * ap[p];
            }
            const float inv = 1.f / denom;
            #pragma unroll
            for (int ct = 0; ct < 8; ++ct) {
                float o = oacc[ct][r] * a0;
                #pragma unroll
                for (int p = 0; p < 3; ++p)
                    o += U.mrg.O[p][wq][lg * 4 + r][ct * 16 + lr] * ap[p];
                orow[(size_t)(lg * 4 + r) * DHEAD + ct * 16 + lr] = o * inv;
            }
        }
    }
}

extern "C" void kernel_launch(void* const* d_in, const int* in_sizes, int n_in,
                              void* d_out, int out_size, void* d_ws, size_t ws_size,
                              hipStream_t stream) {
    const float* x = (const float*)d_in[0];
    float* out = (float*)d_out;
    attn_fwd_kernel<<<dim3(512), 512, 0, stream>>>(x, out);
}

// Round 7
// 338.700 us; speedup vs baseline: 1.7159x; 1.7159x over previous
//
#include <hip/hip_runtime.h>
#include <hip/hip_bf16.h>

typedef __bf16 bf16x8 __attribute__((ext_vector_type(8)));
typedef __bf16 bf16x4 __attribute__((ext_vector_type(4)));
typedef float  f32x4  __attribute__((ext_vector_type(4)));

#define NROW 4096
#define XSTR 384
#define DHEAD 128
#define QBLK 32
#define KVB 128
#define NIT (NROW / KVB)

// 512 threads. 2nd arg = 2 waves/EU guide only -> natural VGPR (~96-110, no spill).
// Residency: LDS 78KB -> 2 blocks/CU; VGPR <=128 -> 4 waves/SIMD. Grid 512 = 2/CU.
__launch_bounds__(512, 2)
__global__ void attn_fwd_kernel(const float* __restrict__ x, float* __restrict__ out) {
    // XCD-aware swizzle: 512 blocks / 8 XCDs -> 64 consecutive logical blocks per XCD
    const int bid  = blockIdx.x;
    const int orig = (bid & 7) * 64 + (bid >> 3);
    const int b    = orig >> 7;          // batch 0..3
    const int t0   = (orig & 127) * QBLK;

    const int tid = threadIdx.x;
    const int w   = tid >> 6;            // wave 0..7
    const int wq  = w & 1;               // q-row group (16 rows)
    const int kvq = w >> 1;              // KV quarter: s in [kvq*32, kvq*32+32)
    const int l   = tid & 63;
    const int lr  = l & 15;
    const int lg  = l >> 4;
    const int sq  = kvq * 32;

    // Kt/Vt stride 136 bf16 = 272B: 16B-aligned rows (real ds_read_b128),
    // bank-step 68%32=4 -> 16-row fragment reads are 2-way (free, m136).
    __shared__ union {
        struct { __bf16 Kt[KVB][136]; __bf16 Vt[DHEAD][136]; } t;   // Kt[s][c], Vt[c][s]
        struct { float O[3][2][16][132]; float m[3][2][16]; float lsum[3][2][16]; } mrg;
    } U;
    // P tile per wave: stride 40 bf16 = 80B: 16B-aligned; read pattern 2-way.
    __shared__ __bf16 Pl[8][16][40];

    const float* xb = x + (size_t)b * NROW * XSTR;

    // ---- Q fragments (k-slice of x, cols 128..255), rows t0 + wq*16 + lr ----
    bf16x8 qf[4];
    {
        const float* qrow = xb + (size_t)(t0 + wq * 16 + lr) * XSTR + DHEAD;
        #pragma unroll
        for (int kc = 0; kc < 4; ++kc) {
            const float4 f0 = *(const float4*)(qrow + kc * 32 + lg * 8);
            const float4 f1 = *(const float4*)(qrow + kc * 32 + lg * 8 + 4);
            bf16x8 v;
            v[0] = (__bf16)f0.x; v[1] = (__bf16)f0.y; v[2] = (__bf16)f0.z; v[3] = (__bf16)f0.w;
            v[4] = (__bf16)f1.x; v[5] = (__bf16)f1.y; v[6] = (__bf16)f1.z; v[7] = (__bf16)f1.w;
            qf[kc] = v;
        }
    }

    f32x4 oacc[8];
    #pragma unroll
    for (int i = 0; i < 8; ++i) { f32x4 z = {0.f, 0.f, 0.f, 0.f}; oacc[i] = z; }
    float mrow[4], lrow[4];
    #pragma unroll
    for (int r = 0; r < 4; ++r) { mrow[r] = -1e30f; lrow[r] = 0.f; }

    const float C = 0.08838834764831845f * 1.44269504088896340f; // 1/sqrt(128)*log2(e)

    const int krow = tid >> 5;           // 0..15
    const int kcol = (tid & 31) << 2;    // 0..124

    float4 pk[8], pv[8];

    auto prefetch = [&](int S0) {
        #pragma unroll
        for (int i = 0; i < 8; ++i)
            pk[i] = *(const float4*)(xb + (size_t)(S0 + krow + i * 16) * XSTR + kcol);
        #pragma unroll
        for (int i2 = 0; i2 < 2; ++i2) {
            const int cb = (krow + i2 * 16) << 2;
            #pragma unroll
            for (int r = 0; r < 4; ++r)
                pv[i2 * 4 + r] = *(const float4*)(xb + (size_t)(S0 + kcol + r) * XSTR + 256 + cb);
        }
    };
    auto write_lds = [&]() {
        #pragma unroll
        for (int i = 0; i < 8; ++i) {
            const float* f = (const float*)&pk[i];
            bf16x4 v;
            v[0] = (__bf16)f[0]; v[1] = (__bf16)f[1]; v[2] = (__bf16)f[2]; v[3] = (__bf16)f[3];
            *(bf16x4*)&U.t.Kt[krow + i * 16][kcol] = v;
        }
        #pragma unroll
        for (int i2 = 0; i2 < 2; ++i2) {
            const int cb = (krow + i2 * 16) << 2;
            #pragma unroll
            for (int cc = 0; cc < 4; ++cc) {
                bf16x4 v;
                #pragma unroll
                for (int r = 0; r < 4; ++r)
                    v[r] = (__bf16)((const float*)&pv[i2 * 4 + r])[cc];
                *(bf16x4*)&U.t.Vt[cb + cc][kcol] = v;   // Vt[c][s]
            }
        }
    };

    prefetch(0);
    write_lds();
    __syncthreads();

    for (int it = 0; it < NIT; ++it) {
        if (it + 1 < NIT) prefetch((it + 1) * KVB);   // hide HBM latency under compute

        // ---- QK^T over this wave's 32-s quarter ----
        f32x4 sacc[2];
        #pragma unroll
        for (int st = 0; st < 2; ++st) { f32x4 z = {0.f, 0.f, 0.f, 0.f}; sacc[st] = z; }
        __builtin_amdgcn_s_setprio(1);
        #pragma unroll
        for (int kc = 0; kc < 4; ++kc) {
            #pragma unroll
            for (int st = 0; st < 2; ++st) {
                bf16x8 bf = *(const bf16x8*)&U.t.Kt[sq + st * 16 + lr][kc * 32 + lg * 8];
                sacc[st] = __builtin_amdgcn_mfma_f32_16x16x32_bf16(qf[kc], bf, sacc[st], 0, 0, 0);
            }
        }
        __builtin_amdgcn_s_setprio(0);

        // ---- online softmax; T13 defer-rescale (exact): keep old max if growth <= 64 raw ----
        float rmax[4], psum[4];
        #pragma unroll
        for (int r = 0; r < 4; ++r) rmax[r] = fmaxf(sacc[0][r], sacc[1][r]);
        #pragma unroll
        for (int mk = 1; mk <= 8; mk <<= 1) {
            #pragma unroll
            for (int r = 0; r < 4; ++r) rmax[r] = fmaxf(rmax[r], __shfl_xor(rmax[r], mk));
        }
        float g = -1e30f;
        #pragma unroll
        for (int r = 0; r < 4; ++r) g = fmaxf(g, rmax[r] - mrow[r]);
        if (!__all(g <= 64.0f)) {
            float alpha[4];
            #pragma unroll
            for (int r = 0; r < 4; ++r) {
                const float mnew = fmaxf(mrow[r], rmax[r]);
                alpha[r] = __builtin_amdgcn_exp2f((mrow[r] - mnew) * C);
                mrow[r]  = mnew;
                lrow[r] *= alpha[r];
            }
            #pragma unroll
            for (int ct = 0; ct < 8; ++ct) {
                #pragma unroll
                for (int r = 0; r < 4; ++r) oacc[ct][r] *= alpha[r];
            }
        }
        #pragma unroll
        for (int r = 0; r < 4; ++r) psum[r] = 0.f;
        #pragma unroll
        for (int st = 0; st < 2; ++st) {
            #pragma unroll
            for (int r = 0; r < 4; ++r) {
                float p = __builtin_amdgcn_exp2f((sacc[st][r] - mrow[r]) * C);
                psum[r] += p;
                Pl[w][lg * 4 + r][st * 16 + lr] = (__bf16)p;
            }
        }
        #pragma unroll
        for (int mk = 1; mk <= 8; mk <<= 1) {
            #pragma unroll
            for (int r = 0; r < 4; ++r) psum[r] += __shfl_xor(psum[r], mk);
        }
        #pragma unroll
        for (int r = 0; r < 4; ++r) lrow[r] += psum[r];

        // ---- PV over this wave's quarter (k=32) ----
        bf16x8 pa = *(const bf16x8*)&Pl[w][lr][lg * 8];
        __builtin_amdgcn_s_setprio(1);
        #pragma unroll
        for (int ct = 0; ct < 8; ++ct) {
            bf16x8 bv = *(const bf16x8*)&U.t.Vt[ct * 16 + lr][sq + lg * 8];
            oacc[ct] = __builtin_amdgcn_mfma_f32_16x16x32_bf16(pa, bv, oacc[ct], 0, 0, 0);
        }
        __builtin_amdgcn_s_setprio(0);

        __syncthreads();                       // all waves done reading Kt/Vt
        if (it + 1 < NIT) { write_lds(); __syncthreads(); }
    }

    // ---- 4-way exact LSE merge across kv quarters ----
    if (kvq > 0) {
        #pragma unroll
        for (int ct = 0; ct < 8; ++ct) {
            #pragma unroll
            for (int r = 0; r < 4; ++r)
                U.mrg.O[kvq - 1][wq][lg * 4 + r][ct * 16 + lr] = oacc[ct][r];
        }
        if (lr == 0) {
            #pragma unroll
            for (int r = 0; r < 4; ++r) {
                U.mrg.m[kvq - 1][wq][lg * 4 + r]    = mrow[r];
                U.mrg.lsum[kvq - 1][wq][lg * 4 + r] = lrow[r];
            }
        }
    }
    __syncthreads();
    if (kvq == 0) {
        float* orow = out + ((size_t)b * NROW + t0 + wq * 16) * DHEAD;
        #pragma unroll
        for (int r = 0; r < 4; ++r) {
            float mp[3], lp[3];
            #pragma unroll
            for (int p = 0; p < 3; ++p) {
                mp[p] = U.mrg.m[p][wq][lg * 4 + r];
                lp[p] = U.mrg.lsum[p][wq][lg * 4 + r];
            }
            float mm = fmaxf(fmaxf(mrow[r], mp[0]), fmaxf(mp[1], mp[2]));
            const float a0 = __builtin_amdgcn_exp2f((mrow[r] - mm) * C);
            float ap[3];
            float denom = lrow[r] * a0;
            #pragma unroll
            for (int p = 0; p < 3; ++p) {
                ap[p] = __builtin_amdgcn_exp2f((mp[p] - mm) * C);
                denom += lp[p] * ap[p];
            }
            const float inv = 1.f / denom;
            #pragma unroll
            for (int ct = 0; ct < 8; ++ct) {
                float o = oacc[ct][r] * a0;
                #pragma unroll
                for (int p = 0; p < 3; ++p)
                    o += U.mrg.O[p][wq][lg * 4 + r][ct * 16 + lr] * ap[p];
                orow[(size_t)(lg * 4 + r) * DHEAD + ct * 16 + lr] = o * inv;
            }
        }
    }
}

extern "C" void kernel_launch(void* const* d_in, const int* in_sizes, int n_in,
                              void* d_out, int out_size, void* d_ws, size_t ws_size,
                              hipStream_t stream) {
    const float* x = (const float*)d_in[0];
    float* out = (float*)d_out;
    attn_fwd_kernel<<<dim3(512), 512, 0, stream>>>(x, out);
}

// Round 8
// 259.292 us; speedup vs baseline: 2.2413x; 1.3062x over previous
//
#include <hip/hip_runtime.h>
#include <hip/hip_bf16.h>

typedef __bf16 bf16x8 __attribute__((ext_vector_type(8)));
typedef __bf16 bf16x4 __attribute__((ext_vector_type(4)));
typedef float  f32x4  __attribute__((ext_vector_type(4)));

#define NROW 4096
#define XSTR 384
#define DHEAD 128
#define QBLK 64
#define KVB 128
#define NIT (NROW / KVB)

// One 1024-thread block per CU (grid 256). 16 waves = 4 q-groups x 4 KV-quarters.
// __launch_bounds__(1024,4) caps VGPR at 128 so all 16 waves are resident
// (a 16-wave block cannot launch otherwise). Live state ~119 VGPR -> no spill.
__launch_bounds__(1024, 4)
__global__ void attn_fwd_kernel(const float* __restrict__ x, float* __restrict__ out) {
    // XCD-aware swizzle: 256 blocks / 8 XCDs -> 32 consecutive logical blocks per XCD
    const int bid  = blockIdx.x;
    const int orig = (bid & 7) * 32 + (bid >> 3);
    const int b    = orig >> 6;          // batch 0..3
    const int t0   = (orig & 63) * QBLK;

    const int tid = threadIdx.x;
    const int w   = tid >> 6;            // wave 0..15
    const int wq  = w & 3;               // q-row group (16 rows)
    const int kvq = w >> 2;              // KV quarter: s in [kvq*32, kvq*32+32)
    const int l   = tid & 63;
    const int lr  = l & 15;
    const int lg  = l >> 4;
    const int sq  = kvq * 32;

    // Kt/Vt stride 136 bf16 = 272B: 16B-aligned rows (true ds_read_b128),
    // bank-step (68 dwords)%32=4 -> 16-row fragment reads are 2-way (free, m136).
    __shared__ union {
        struct { __bf16 Kt[KVB][136]; __bf16 Vt[DHEAD][136]; } t;   // Kt[s][c], Vt[c][s]
        struct { float O[2][4][16][132]; float m[2][4][16]; float lsum[2][4][16]; } mrg;
    } U;
    // P tile per wave: stride 40 bf16 = 80B, 16B-aligned; b128 reads 2-way.
    __shared__ __bf16 Pl[16][16][40];

    const float* xb = x + (size_t)b * NROW * XSTR;

    // ---- Q fragments (k-slice of x, cols 128..255), rows t0 + wq*16 + lr ----
    bf16x8 qf[4];
    {
        const float* qrow = xb + (size_t)(t0 + wq * 16 + lr) * XSTR + DHEAD;
        #pragma unroll
        for (int kc = 0; kc < 4; ++kc) {
            const float4 f0 = *(const float4*)(qrow + kc * 32 + lg * 8);
            const float4 f1 = *(const float4*)(qrow + kc * 32 + lg * 8 + 4);
            bf16x8 v;
            v[0] = (__bf16)f0.x; v[1] = (__bf16)f0.y; v[2] = (__bf16)f0.z; v[3] = (__bf16)f0.w;
            v[4] = (__bf16)f1.x; v[5] = (__bf16)f1.y; v[6] = (__bf16)f1.z; v[7] = (__bf16)f1.w;
            qf[kc] = v;
        }
    }

    f32x4 oacc[8];
    #pragma unroll
    for (int i = 0; i < 8; ++i) { f32x4 z = {0.f, 0.f, 0.f, 0.f}; oacc[i] = z; }
    float mrow[4], lrow[4];
    #pragma unroll
    for (int r = 0; r < 4; ++r) { mrow[r] = -1e30f; lrow[r] = 0.f; }

    const float C = 0.08838834764831845f * 1.44269504088896340f; // 1/sqrt(128)*log2(e)

    const int krow = tid >> 5;           // 0..31
    const int kcol = (tid & 31) << 2;    // 0..124

    float4 pk[4], pv[4];

    auto prefetch = [&](int S0) {
        #pragma unroll
        for (int i = 0; i < 4; ++i)
            pk[i] = *(const float4*)(xb + (size_t)(S0 + krow + i * 32) * XSTR + kcol);
        #pragma unroll
        for (int r = 0; r < 4; ++r)
            pv[r] = *(const float4*)(xb + (size_t)(S0 + kcol + r) * XSTR + 256 + krow * 4);
    };
    auto write_lds = [&]() {
        #pragma unroll
        for (int i = 0; i < 4; ++i) {
            const float* f = (const float*)&pk[i];
            bf16x4 v;
            v[0] = (__bf16)f[0]; v[1] = (__bf16)f[1]; v[2] = (__bf16)f[2]; v[3] = (__bf16)f[3];
            *(bf16x4*)&U.t.Kt[krow + i * 32][kcol] = v;
        }
        const int cb = krow * 4;
        #pragma unroll
        for (int cc = 0; cc < 4; ++cc) {
            bf16x4 v;
            #pragma unroll
            for (int r = 0; r < 4; ++r)
                v[r] = (__bf16)((const float*)&pv[r])[cc];
            *(bf16x4*)&U.t.Vt[cb + cc][kcol] = v;   // Vt[c][s], s = kcol..kcol+3
        }
    };

    prefetch(0);
    write_lds();
    __syncthreads();

    for (int it = 0; it < NIT; ++it) {
        if (it + 1 < NIT) prefetch((it + 1) * KVB);   // hide HBM latency under compute

        // ---- QK^T over this wave's 32-s quarter ----
        f32x4 sacc[2];
        #pragma unroll
        for (int st = 0; st < 2; ++st) { f32x4 z = {0.f, 0.f, 0.f, 0.f}; sacc[st] = z; }
        __builtin_amdgcn_s_setprio(1);
        #pragma unroll
        for (int kc = 0; kc < 4; ++kc) {
            #pragma unroll
            for (int st = 0; st < 2; ++st) {
                bf16x8 bf = *(const bf16x8*)&U.t.Kt[sq + st * 16 + lr][kc * 32 + lg * 8];
                sacc[st] = __builtin_amdgcn_mfma_f32_16x16x32_bf16(qf[kc], bf, sacc[st], 0, 0, 0);
            }
        }
        __builtin_amdgcn_s_setprio(0);

        // ---- online softmax; defer-rescale (exact): keep old max if growth <= 64 raw ----
        float rmax[4], psum[4];
        #pragma unroll
        for (int r = 0; r < 4; ++r) rmax[r] = fmaxf(sacc[0][r], sacc[1][r]);
        #pragma unroll
        for (int mk = 1; mk <= 8; mk <<= 1) {
            #pragma unroll
            for (int r = 0; r < 4; ++r) rmax[r] = fmaxf(rmax[r], __shfl_xor(rmax[r], mk));
        }
        float g = -1e30f;
        #pragma unroll
        for (int r = 0; r < 4; ++r) g = fmaxf(g, rmax[r] - mrow[r]);
        if (!__all(g <= 64.0f)) {
            float alpha[4];
            #pragma unroll
            for (int r = 0; r < 4; ++r) {
                const float mnew = fmaxf(mrow[r], rmax[r]);
                alpha[r] = __builtin_amdgcn_exp2f((mrow[r] - mnew) * C);
                mrow[r]  = mnew;
                lrow[r] *= alpha[r];
            }
            #pragma unroll
            for (int ct = 0; ct < 8; ++ct) {
                #pragma unroll
                for (int r = 0; r < 4; ++r) oacc[ct][r] *= alpha[r];
            }
        }
        #pragma unroll
        for (int r = 0; r < 4; ++r) psum[r] = 0.f;
        #pragma unroll
        for (int st = 0; st < 2; ++st) {
            #pragma unroll
            for (int r = 0; r < 4; ++r) {
                float p = __builtin_amdgcn_exp2f((sacc[st][r] - mrow[r]) * C);
                psum[r] += p;
                Pl[w][lg * 4 + r][st * 16 + lr] = (__bf16)p;
            }
        }
        #pragma unroll
        for (int mk = 1; mk <= 8; mk <<= 1) {
            #pragma unroll
            for (int r = 0; r < 4; ++r) psum[r] += __shfl_xor(psum[r], mk);
        }
        #pragma unroll
        for (int r = 0; r < 4; ++r) lrow[r] += psum[r];

        // ---- PV over this wave's quarter (k=32) ----
        bf16x8 pa = *(const bf16x8*)&Pl[w][lr][lg * 8];
        __builtin_amdgcn_s_setprio(1);
        #pragma unroll
        for (int ct = 0; ct < 8; ++ct) {
            bf16x8 bv = *(const bf16x8*)&U.t.Vt[ct * 16 + lr][sq + lg * 8];
            oacc[ct] = __builtin_amdgcn_mfma_f32_16x16x32_bf16(pa, bv, oacc[ct], 0, 0, 0);
        }
        __builtin_amdgcn_s_setprio(0);

        __syncthreads();                       // all waves done reading Kt/Vt
        if (it + 1 < NIT) { write_lds(); __syncthreads(); }
    }

    // ---- 4-way exact LSE merge, 2-stage pairwise (1->0, 3->2, then 2->0) ----
    // Stage A write: odd quarters publish partials.
    if (kvq & 1) {
        const int slot = kvq >> 1;
        #pragma unroll
        for (int ct = 0; ct < 8; ++ct) {
            #pragma unroll
            for (int r = 0; r < 4; ++r)
                U.mrg.O[slot][wq][lg * 4 + r][ct * 16 + lr] = oacc[ct][r];
        }
        if (lr == 0) {
            #pragma unroll
            for (int r = 0; r < 4; ++r) {
                U.mrg.m[slot][wq][lg * 4 + r]    = mrow[r];
                U.mrg.lsum[slot][wq][lg * 4 + r] = lrow[r];
            }
        }
    }
    __syncthreads();
    // Stage A merge: even quarters absorb their partner.
    if (!(kvq & 1)) {
        const int slot = kvq >> 1;
        #pragma unroll
        for (int r = 0; r < 4; ++r) {
            const int  row = lg * 4 + r;
            const float m2 = U.mrg.m[slot][wq][row];
            const float l2 = U.mrg.lsum[slot][wq][row];
            const float mm = fmaxf(mrow[r], m2);
            const float a1 = __builtin_amdgcn_exp2f((mrow[r] - mm) * C);
            const float a2 = __builtin_amdgcn_exp2f((m2 - mm) * C);
            mrow[r] = mm;
            lrow[r] = lrow[r] * a1 + l2 * a2;
            #pragma unroll
            for (int ct = 0; ct < 8; ++ct)
                oacc[ct][r] = oacc[ct][r] * a1 + U.mrg.O[slot][wq][row][ct * 16 + lr] * a2;
        }
    }
    __syncthreads();
    // Stage B write: quarter 2 publishes its merged partial to slot 0.
    if (kvq == 2) {
        #pragma unroll
        for (int ct = 0; ct < 8; ++ct) {
            #pragma unroll
            for (int r = 0; r < 4; ++r)
                U.mrg.O[0][wq][lg * 4 + r][ct * 16 + lr] = oacc[ct][r];
        }
        if (lr == 0) {
            #pragma unroll
            for (int r = 0; r < 4; ++r) {
                U.mrg.m[0][wq][lg * 4 + r]    = mrow[r];
                U.mrg.lsum[0][wq][lg * 4 + r] = lrow[r];
            }
        }
    }
    __syncthreads();
    // Stage B merge + epilogue: quarter 0 finalizes and writes out.
    if (kvq == 0) {
        float* orow = out + ((size_t)b * NROW + t0 + wq * 16) * DHEAD;
        #pragma unroll
        for (int r = 0; r < 4; ++r) {
            const int  row = lg * 4 + r;
            const float m2 = U.mrg.m[0][wq][row];
            const float l2 = U.mrg.lsum[0][wq][row];
            const float mm = fmaxf(mrow[r], m2);
            const float a1 = __builtin_amdgcn_exp2f((mrow[r] - mm) * C);
            const float a2 = __builtin_amdgcn_exp2f((m2 - mm) * C);
            const float inv = 1.f / (lrow[r] * a1 + l2 * a2);
            #pragma unroll
            for (int ct = 0; ct < 8; ++ct) {
                const float o = oacc[ct][r] * a1 + U.mrg.O[0][wq][row][ct * 16 + lr] * a2;
                orow[(size_t)row * DHEAD + ct * 16 + lr] = o * inv;
            }
        }
    }
}

extern "C" void kernel_launch(void* const* d_in, const int* in_sizes, int n_in,
                              void* d_out, int out_size, void* d_ws, size_t ws_size,
                              hipStream_t stream) {
    const float* x = (const float*)d_in[0];
    float* out = (float*)d_out;
    attn_fwd_kernel<<<dim3(256), 1024, 0, stream>>>(x, out);
}